// Round 1
// baseline (1753.403 us; speedup 1.0000x reference)
//
#include <hip/hip_runtime.h>
#include <math.h>

#define EMB 512
#define SEQL 1024
#define NBATCH 2
#define NHEAD 8
#define HDIM 64
#define FFDIM 2048
#define NLAYER 4
#define NROWS (NBATCH*SEQL)
#define CHUNK 128
#define NCH (SEQL/CHUNK)
#define LN_EPS_F 1e-5f
#define ATT_EPS_F 1e-6f

// ---------------- embedding + shift-right(SOS) ----------------
__global__ void k_embed(const int* __restrict__ value, const int* __restrict__ depth,
                        const int* __restrict__ pos, const float* __restrict__ sos,
                        const float* __restrict__ tok, const float* __restrict__ dep,
                        const float* __restrict__ spa, float* __restrict__ X) {
    int row = blockIdx.x;
    int n = row / SEQL, s = row % SEQL;
    int e = threadIdx.x * 4;
    float4 o;
    if (s == 0) {
        o = *(const float4*)(sos + e);
    } else {
        int sp = s - 1;
        int tv = value[n*SEQL + sp];
        int dv = depth[n*SEQL + sp];
        float4 a = *(const float4*)(tok + (size_t)tv*EMB + e);
        float4 b = *(const float4*)(dep + (size_t)dv*EMB + e);
        o.x = a.x+b.x; o.y = a.y+b.y; o.z = a.z+b.z; o.w = a.w+b.w;
#pragma unroll
        for (int ax = 0; ax < 3; ++ax) {
            int p = pos[((size_t)ax*NBATCH + n)*SEQL + sp];
            float4 c = *(const float4*)(spa + ((size_t)ax*257 + p)*EMB + e);
            o.x += c.x; o.y += c.y; o.z += c.z; o.w += c.w;
        }
    }
    *(float4*)(X + (size_t)row*EMB + e) = o;
}

// ---------------- fp32 tiled GEMM: C = act(A[M,K]@W[K,N] + bias) ----------------
// ACT: 0=none, 1=elu+1, 2=(elu+1)*kmask(row), 3=gelu(exact)
template<int ACT>
__global__ __launch_bounds__(256) void k_gemm(
        const float* __restrict__ A, const float* __restrict__ W,
        const float* __restrict__ bias, const int* __restrict__ maskv,
        float* __restrict__ C, int N, int K) {
    __shared__ float As[16][68];   // [k][m], padded stride 68 (16B-aligned rows)
    __shared__ float Ws[16][68];   // [k][n]
    int bm = blockIdx.y * 64, bn = blockIdx.x * 64;
    int tid = threadIdx.x;
    int tm = (tid >> 4) * 4, tn = (tid & 15) * 4;
    int am = tid >> 2, ak = (tid & 3) * 4;
    int wk = tid >> 4, wn = (tid & 15) * 4;
    float acc[4][4] = {};
    for (int k0 = 0; k0 < K; k0 += 16) {
        float4 av = *(const float4*)(A + (size_t)(bm + am)*K + k0 + ak);
        As[ak+0][am] = av.x; As[ak+1][am] = av.y; As[ak+2][am] = av.z; As[ak+3][am] = av.w;
        *(float4*)&Ws[wk][wn] = *(const float4*)(W + (size_t)(k0 + wk)*N + bn + wn);
        __syncthreads();
#pragma unroll
        for (int kk = 0; kk < 16; ++kk) {
            float4 a4 = *(float4*)&As[kk][tm];
            float4 b4 = *(float4*)&Ws[kk][tn];
            float ar[4] = {a4.x, a4.y, a4.z, a4.w};
            float br[4] = {b4.x, b4.y, b4.z, b4.w};
#pragma unroll
            for (int i = 0; i < 4; ++i)
#pragma unroll
                for (int j = 0; j < 4; ++j)
                    acc[i][j] += ar[i] * br[j];
        }
        __syncthreads();
    }
#pragma unroll
    for (int i = 0; i < 4; ++i) {
        int r = bm + tm + i;
        float mrow = 1.f;
        if (ACT == 2) mrow = (maskv[r] != 0) ? 1.f : 0.f;
        float4 o;
        float cv[4];
#pragma unroll
        for (int j = 0; j < 4; ++j) {
            float c = acc[i][j] + bias[bn + tn + j];
            if (ACT == 1 || ACT == 2) {
                c = (c > 0.f) ? (c + 1.f) : expf(c);
                if (ACT == 2) c *= mrow;
            } else if (ACT == 3) {
                c = 0.5f * c * (1.f + erff(c * 0.70710678118654752f));
            }
            cv[j] = c;
        }
        o.x = cv[0]; o.y = cv[1]; o.z = cv[2]; o.w = cv[3];
        *(float4*)(C + (size_t)r*N + bn + tn) = o;
    }
}

// ---------------- per-chunk partial K^T V (64x64) and sum(k) (64) ----------------
__global__ __launch_bounds__(256) void k_cpart(
        const float* __restrict__ Km, const float* __restrict__ Vm,
        float* __restrict__ Mpart, float* __restrict__ Upart) {
    int b = blockIdx.x;
    int c = b % NCH, h = (b / NCH) % NHEAD, n = b / (NCH * NHEAD);
    const float* Kp = Km + (size_t)(n*SEQL + c*CHUNK)*EMB + h*HDIM;
    const float* Vp = Vm + (size_t)(n*SEQL + c*CHUNK)*EMB + h*HDIM;
    __shared__ float Ks[8][64], Vs[8][64];
    int tid = threadIdx.x;
    int dk = tid >> 2, dv0 = (tid & 3) * 16;
    int lr = tid >> 5, lc = (tid & 31) * 2;
    float acc[16] = {};
    float uacc = 0.f;
    for (int s0 = 0; s0 < CHUNK; s0 += 8) {
        float2 k2 = *(const float2*)(Kp + (size_t)(s0 + lr)*EMB + lc);
        float2 v2 = *(const float2*)(Vp + (size_t)(s0 + lr)*EMB + lc);
        Ks[lr][lc] = k2.x; Ks[lr][lc+1] = k2.y;
        Vs[lr][lc] = v2.x; Vs[lr][lc+1] = v2.y;
        __syncthreads();
#pragma unroll
        for (int ss = 0; ss < 8; ++ss) {
            float kk = Ks[ss][dk];
#pragma unroll
            for (int j = 0; j < 16; ++j) acc[j] += kk * Vs[ss][dv0 + j];
        }
        if (tid < 64) {
#pragma unroll
            for (int ss = 0; ss < 8; ++ss) uacc += Ks[ss][tid];
        }
        __syncthreads();
    }
    size_t base = ((size_t)(n*NHEAD + h)*NCH + c) * 4096;
#pragma unroll
    for (int j = 0; j < 16; ++j) Mpart[base + (size_t)dk*64 + dv0 + j] = acc[j];
    if (tid < 64) Upart[((size_t)(n*NHEAD + h)*NCH + c)*64 + tid] = uacc;
}

// ---------------- exclusive prefix scan over chunks ----------------
__global__ __launch_bounds__(256) void k_cscan(
        const float* __restrict__ Mpart, const float* __restrict__ Upart,
        float* __restrict__ Mpref, float* __restrict__ Upref) {
    int nh = blockIdx.x, tid = threadIdx.x;
    size_t base = (size_t)nh * NCH * 4096;
    for (int t = 0; t < 16; ++t) {
        int idx = t*256 + tid;
        float run = 0.f;
#pragma unroll
        for (int c = 0; c < NCH; ++c) {
            Mpref[base + (size_t)c*4096 + idx] = run;
            run += Mpart[base + (size_t)c*4096 + idx];
        }
    }
    if (tid < 64) {
        size_t ub = (size_t)nh * NCH * 64;
        float run = 0.f;
#pragma unroll
        for (int c = 0; c < NCH; ++c) {
            Upref[ub + c*64 + tid] = run;
            run += Upart[ub + c*64 + tid];
        }
    }
}

// ---------------- per-chunk attention: (QK^T ⊙ causal)V + Q@P, z from rowsum ----------------
__global__ __launch_bounds__(128) void k_cattend(
        const float* __restrict__ Qm, const float* __restrict__ Km,
        const float* __restrict__ Vm, const float* __restrict__ Mpref,
        const float* __restrict__ Upref, float* __restrict__ Am) {
    int b = blockIdx.x;
    int c = b % NCH, h = (b / NCH) % NHEAD, n = b / (NCH * NHEAD);
    int tid = threadIdx.x;   // 0..127, one row each
    __shared__ float Pp[64*64];
    __shared__ float wv[64];
    __shared__ float Kt[16][64];
    __shared__ float Vt[16][64];
    size_t pbase = ((size_t)(n*NHEAD + h)*NCH + c) * 4096;
#pragma unroll
    for (int t = 0; t < 32; ++t) Pp[t*128 + tid] = Mpref[pbase + t*128 + tid];
    if (tid < 64) wv[tid] = Upref[((size_t)(n*NHEAD + h)*NCH + c)*64 + tid];
    int rowbase = n*SEQL + c*CHUNK;
    int i = tid;
    float q[64];
    const float* qp = Qm + (size_t)(rowbase + i)*EMB + h*HDIM;
#pragma unroll
    for (int d = 0; d < 64; d += 4) {
        float4 t4 = *(const float4*)(qp + d);
        q[d] = t4.x; q[d+1] = t4.y; q[d+2] = t4.z; q[d+3] = t4.w;
    }
    float acc[64] = {};
    float rowsum = 0.f;
    int jr = tid >> 3, jc = (tid & 7) * 8;
    for (int j0 = 0; j0 < CHUNK; j0 += 16) {
        const float* kp = Km + (size_t)(rowbase + j0 + jr)*EMB + h*HDIM + jc;
        const float* vp = Vm + (size_t)(rowbase + j0 + jr)*EMB + h*HDIM + jc;
        __syncthreads();
        *(float4*)&Kt[jr][jc]   = *(const float4*)kp;
        *(float4*)&Kt[jr][jc+4] = *(const float4*)(kp + 4);
        *(float4*)&Vt[jr][jc]   = *(const float4*)vp;
        *(float4*)&Vt[jr][jc+4] = *(const float4*)(vp + 4);
        __syncthreads();
        for (int jj = 0; jj < 16; ++jj) {
            int j = j0 + jj;
            if (j > i) break;
            float s = 0.f;
#pragma unroll
            for (int d = 0; d < 64; ++d) s += q[d] * Kt[jj][d];
            rowsum += s;
#pragma unroll
            for (int d = 0; d < 64; ++d) acc[d] += s * Vt[jj][d];
        }
    }
    // prefix-state contribution: acc += q @ P
    for (int dd = 0; dd < 64; ++dd) {
        float qd = q[dd];
        const float* pr = &Pp[dd*64];
#pragma unroll
        for (int d = 0; d < 64; ++d) acc[d] += qd * pr[d];
    }
    float den = rowsum;
#pragma unroll
    for (int d = 0; d < 64; ++d) den += q[d] * wv[d];
    float z = 1.f / (den + ATT_EPS_F);
    float* op = Am + (size_t)(rowbase + i)*EMB + h*HDIM;
#pragma unroll
    for (int d = 0; d < 64; d += 4) {
        float4 o; o.x = acc[d]*z; o.y = acc[d+1]*z; o.z = acc[d+2]*z; o.w = acc[d+3]*z;
        *(float4*)(op + d) = o;
    }
}

// ---------------- residual + LayerNorm (R may be null) ----------------
__global__ __launch_bounds__(256) void k_ln(
        const float* __restrict__ X, const float* __restrict__ R,
        const float* __restrict__ g, const float* __restrict__ bb,
        float* __restrict__ Y) {
    int row = blockIdx.x, tid = threadIdx.x;
    float2 v = *(const float2*)(X + (size_t)row*EMB + tid*2);
    if (R) {
        float2 r = *(const float2*)(R + (size_t)row*EMB + tid*2);
        v.x += r.x; v.y += r.y;
    }
    float s = v.x + v.y, ss = v.x*v.x + v.y*v.y;
#pragma unroll
    for (int off = 32; off; off >>= 1) {
        s  += __shfl_down(s, off);
        ss += __shfl_down(ss, off);
    }
    __shared__ float sb[4], ssb[4];
    int wid = tid >> 6, lane = tid & 63;
    if (!lane) { sb[wid] = s; ssb[wid] = ss; }
    __syncthreads();
    float tot  = sb[0] + sb[1] + sb[2] + sb[3];
    float tots = ssb[0] + ssb[1] + ssb[2] + ssb[3];
    float mean = tot * (1.f/EMB);
    float var  = tots * (1.f/EMB) - mean*mean;
    float inv  = rsqrtf(var + LN_EPS_F);
    int e = tid*2;
    float2 o;
    o.x = (v.x - mean)*inv*g[e]   + bb[e];
    o.y = (v.y - mean)*inv*g[e+1] + bb[e+1];
    *(float2*)(Y + (size_t)row*EMB + e) = o;
}

// ---------------- head: out = X @ Wh  (512 -> 17) ----------------
__global__ void k_head(const float* __restrict__ X, const float* __restrict__ Wh,
                       float* __restrict__ out) {
    int idx = blockIdx.x * blockDim.x + threadIdx.x;
    if (idx >= NROWS*17) return;
    int row = idx / 17, c = idx - row*17;
    const float* xp = X + (size_t)row*EMB;
    float acc = 0.f;
    for (int k = 0; k < EMB; ++k) acc += xp[k] * Wh[k*17 + c];
    out[idx] = acc;
}

extern "C" void kernel_launch(void* const* d_in, const int* in_sizes, int n_in,
                              void* d_out, int out_size, void* d_ws, size_t ws_size,
                              hipStream_t stream) {
    (void)in_sizes; (void)n_in; (void)out_size; (void)ws_size;
    const int*   value = (const int*)d_in[0];
    const int*   depth = (const int*)d_in[1];
    const int*   pos   = (const int*)d_in[2];
    const float* sos   = (const float*)d_in[3];
    const float* tok   = (const float*)d_in[4];
    const float* dep   = (const float*)d_in[5];
    const float* spa   = (const float*)d_in[6];
    const float* Wq0   = (const float*)d_in[7];
    const float* Wk0   = (const float*)d_in[8];
    const float* Wv0   = (const float*)d_in[9];
    const float* Wo0   = (const float*)d_in[10];
    const float* bq0   = (const float*)d_in[11];
    const float* bk0   = (const float*)d_in[12];
    const float* bv0   = (const float*)d_in[13];
    const float* bo0   = (const float*)d_in[14];
    const float* ln1g  = (const float*)d_in[15];
    const float* ln1b  = (const float*)d_in[16];
    const float* ln2g  = (const float*)d_in[17];
    const float* ln2b  = (const float*)d_in[18];
    const float* W10   = (const float*)d_in[19];
    const float* b10   = (const float*)d_in[20];
    const float* W20   = (const float*)d_in[21];
    const float* b20   = (const float*)d_in[22];
    const float* lnfg  = (const float*)d_in[23];
    const float* lnfb  = (const float*)d_in[24];
    const float* Wh    = (const float*)d_in[25];
    float* out = (float*)d_out;
    float* ws  = (float*)d_ws;

    float* X     = ws + 0;         // 1M floats
    float* Q     = ws + 1048576;   // 1M
    float* Kb    = ws + 2097152;   // 1M
    float* Vb    = ws + 3145728;   // 1M
    float* Ab    = ws + 4194304;   // 1M
    float* AO    = ws + 5242880;   // 1M
    float* Hb    = ws + 1048576;   // 4M, aliases Q/K/V/Ab (dead by FF time)
    float* Mpart = ws + 6291456;   // 524288
    float* Upart = ws + 6815744;   // 8192
    float* Mpref = ws + 6823936;   // 524288
    float* Upref = ws + 7348224;   // 8192  -> total ~28.1 MiB

    k_embed<<<NROWS, 128, 0, stream>>>(value, depth, pos, sos, tok, dep, spa, X);

    dim3 g512(8, 32), gff(32, 32);
    for (int L = 0; L < NLAYER; ++L) {
        const float* Wq = Wq0 + (size_t)L*EMB*EMB;
        const float* Wk = Wk0 + (size_t)L*EMB*EMB;
        const float* Wv = Wv0 + (size_t)L*EMB*EMB;
        const float* Wo = Wo0 + (size_t)L*EMB*EMB;
        const float* bq = bq0 + (size_t)L*EMB;
        const float* bk = bk0 + (size_t)L*EMB;
        const float* bv = bv0 + (size_t)L*EMB;
        const float* bo = bo0 + (size_t)L*EMB;
        const float* W1 = W10 + (size_t)L*EMB*FFDIM;
        const float* b1 = b10 + (size_t)L*FFDIM;
        const float* W2 = W20 + (size_t)L*FFDIM*EMB;
        const float* b2 = b20 + (size_t)L*EMB;

        k_gemm<1><<<g512, 256, 0, stream>>>(X, Wq, bq, nullptr, Q, EMB, EMB);
        k_gemm<2><<<g512, 256, 0, stream>>>(X, Wk, bk, value,   Kb, EMB, EMB);
        k_gemm<0><<<g512, 256, 0, stream>>>(X, Wv, bv, nullptr, Vb, EMB, EMB);
        k_cpart<<<NBATCH*NHEAD*NCH, 256, 0, stream>>>(Kb, Vb, Mpart, Upart);
        k_cscan<<<NBATCH*NHEAD, 256, 0, stream>>>(Mpart, Upart, Mpref, Upref);
        k_cattend<<<NBATCH*NHEAD*NCH, 128, 0, stream>>>(Q, Kb, Vb, Mpref, Upref, Ab);
        k_gemm<0><<<g512, 256, 0, stream>>>(Ab, Wo, bo, nullptr, AO, EMB, EMB);
        k_ln<<<NROWS, 256, 0, stream>>>(X, AO, ln1g + (size_t)L*EMB, ln1b + (size_t)L*EMB, X);
        k_gemm<3><<<gff,  256, 0, stream>>>(X,  W1, b1, nullptr, Hb, FFDIM, EMB);
        k_gemm<0><<<g512, 256, 0, stream>>>(Hb, W2, b2, nullptr, AO, EMB, FFDIM);
        k_ln<<<NROWS, 256, 0, stream>>>(X, AO, ln2g + (size_t)L*EMB, ln2b + (size_t)L*EMB, X);
    }
    k_ln<<<NROWS, 256, 0, stream>>>(X, nullptr, lnfg, lnfb, X);
    k_head<<<(NROWS*17 + 255)/256, 256, 0, stream>>>(X, Wh, out);
}

// Round 2
// 947.305 us; speedup vs baseline: 1.8509x; 1.8509x over previous
//
#include <hip/hip_runtime.h>
#include <math.h>

#define EMB 512
#define SEQL 1024
#define NBATCH 2
#define NHEAD 8
#define FFDIM 2048
#define NLAYER 4
#define NROWS (NBATCH*SEQL)
#define CHUNK 128
#define NCH (SEQL/CHUNK)
#define QSTR 1536
#define LN_EPS_F 1e-5f
#define ATT_EPS_F 1e-6f

typedef __bf16 bf16x8 __attribute__((ext_vector_type(8)));
typedef float f32x4 __attribute__((ext_vector_type(4)));

__device__ __forceinline__ unsigned short f2bf(float f) {
    unsigned int u = __float_as_uint(f);
    u += 0x7FFFu + ((u >> 16) & 1u);
    return (unsigned short)(u >> 16);
}
__device__ __forceinline__ float bf2f(unsigned short x) {
    return __uint_as_float(((unsigned int)x) << 16);
}
__device__ __forceinline__ void gl_lds16(const unsigned short* g, unsigned short* l) {
    __builtin_amdgcn_global_load_lds(
        (__attribute__((address_space(1))) void*)const_cast<unsigned short*>(g),
        (__attribute__((address_space(3))) void*)l, 16, 0, 0);
}

// ---------------- embedding + shift-right(SOS), writes fp32 X and bf16 Xb ----------------
__global__ void k_embed(const int* __restrict__ value, const int* __restrict__ depth,
                        const int* __restrict__ pos, const float* __restrict__ sos,
                        const float* __restrict__ tok, const float* __restrict__ dep,
                        const float* __restrict__ spa, float* __restrict__ X,
                        unsigned short* __restrict__ Xb) {
    int row = blockIdx.x;
    int n = row / SEQL, s = row % SEQL;
    int e = threadIdx.x * 4;
    float4 o;
    if (s == 0) {
        o = *(const float4*)(sos + e);
    } else {
        int sp = s - 1;
        int tv = value[n*SEQL + sp];
        int dv = depth[n*SEQL + sp];
        float4 a = *(const float4*)(tok + (size_t)tv*EMB + e);
        float4 b = *(const float4*)(dep + (size_t)dv*EMB + e);
        o.x = a.x+b.x; o.y = a.y+b.y; o.z = a.z+b.z; o.w = a.w+b.w;
#pragma unroll
        for (int ax = 0; ax < 3; ++ax) {
            int p = pos[((size_t)ax*NBATCH + n)*SEQL + sp];
            float4 c = *(const float4*)(spa + ((size_t)ax*257 + p)*EMB + e);
            o.x += c.x; o.y += c.y; o.z += c.z; o.w += c.w;
        }
    }
    *(float4*)(X + (size_t)row*EMB + e) = o;
    ushort4 ob; ob.x = f2bf(o.x); ob.y = f2bf(o.y); ob.z = f2bf(o.z); ob.w = f2bf(o.w);
    *(ushort4*)(Xb + (size_t)row*EMB + e) = ob;
}

// ---------------- weight convert: fp32 [K][Ns] -> bf16 packed [K/8][Nd][8] ----------------
// regions: 0..3 = Wq,Wk,Wv (->qkvT noff 0/512/1024) and Wo; 4 = W1; 5 = W2
__global__ __launch_bounds__(256) void k_wconv(
        const float* __restrict__ Wq, const float* __restrict__ Wk, const float* __restrict__ Wv,
        const float* __restrict__ Wo, const float* __restrict__ W1, const float* __restrict__ W2,
        unsigned short* __restrict__ qkvT, unsigned short* __restrict__ woT,
        unsigned short* __restrict__ w1T, unsigned short* __restrict__ w2T) {
    int idx = blockIdx.x*256 + threadIdx.x;
    const float* src; unsigned short* dst; size_t soff; size_t doff;
    if (idx < 131072) {                      // 4 x (64 kb x 512 n)
        int sub = idx >> 15, t = idx & 32767;
        int kb = t >> 9, n = t & 511;
        src = (sub == 0) ? Wq : (sub == 1) ? Wk : (sub == 2) ? Wv : Wo;
        soff = (size_t)kb*8*512 + n;
        if (sub < 3) { dst = qkvT; doff = ((size_t)kb*1536 + sub*512 + n)*8; }
        else         { dst = woT;  doff = ((size_t)kb*512 + n)*8; }
        unsigned int p[4];
#pragma unroll
        for (int t2 = 0; t2 < 4; ++t2) {
            unsigned int lo = f2bf(src[soff + (size_t)(2*t2)*512]);
            unsigned int hi = f2bf(src[soff + (size_t)(2*t2+1)*512]);
            p[t2] = lo | (hi << 16);
        }
        *(uint4*)(dst + doff) = make_uint4(p[0], p[1], p[2], p[3]);
    } else if (idx < 262144) {               // W1: 64 kb x 2048 n
        int t = idx - 131072;
        int kb = t >> 11, n = t & 2047;
        soff = (size_t)kb*8*2048 + n;
        doff = ((size_t)kb*2048 + n)*8;
        unsigned int p[4];
#pragma unroll
        for (int t2 = 0; t2 < 4; ++t2) {
            unsigned int lo = f2bf(W1[soff + (size_t)(2*t2)*2048]);
            unsigned int hi = f2bf(W1[soff + (size_t)(2*t2+1)*2048]);
            p[t2] = lo | (hi << 16);
        }
        *(uint4*)(w1T + doff) = make_uint4(p[0], p[1], p[2], p[3]);
    } else {                                  // W2: 256 kb x 512 n
        int t = idx - 262144;
        int kb = t >> 9, n = t & 511;
        soff = (size_t)kb*8*512 + n;
        doff = ((size_t)kb*512 + n)*8;
        unsigned int p[4];
#pragma unroll
        for (int t2 = 0; t2 < 4; ++t2) {
            unsigned int lo = f2bf(W2[soff + (size_t)(2*t2)*512]);
            unsigned int hi = f2bf(W2[soff + (size_t)(2*t2+1)*512]);
            p[t2] = lo | (hi << 16);
        }
        *(uint4*)(w2T + doff) = make_uint4(p[0], p[1], p[2], p[3]);
    }
}

// ---------------- pack qkv biases [L][1536] ----------------
__global__ void k_bpack(const float* __restrict__ bq, const float* __restrict__ bk,
                        const float* __restrict__ bv, float* __restrict__ outp) {
    int c = blockIdx.x*256 + threadIdx.x;   // grid.x = 6 -> c < 1536
    int L = blockIdx.y;
    float v = (c < 512) ? bq[L*512 + c] : (c < 1024) ? bk[L*512 + c - 512] : bv[L*512 + c - 1024];
    outp[L*1536 + c] = v;
}

// ---------------- bf16 MFMA GEMM: C = act(A[M,lda]bf16 @ Wt[K/8][N][8]bf16 + bias) ----------------
// ACT: 0 = none -> fp32 Cf ; 3 = gelu -> bf16 Cb ; 4 = fused QKV epilogue -> bf16 Cb (stride ldc)
template<int BM, int BN, int ACT>
__global__ __launch_bounds__(256) void k_mgemm(
        const unsigned short* __restrict__ A, const unsigned short* __restrict__ Wt,
        const float* __restrict__ bias, const int* __restrict__ maskv,
        float* __restrict__ Cf, unsigned short* __restrict__ Cb,
        int N, int K, int lda, int ldc) {
    constexpr int WM = BM/2, WN = BN/2;
    constexpr int FM = WM/16, FN = WN/16;
    __shared__ __align__(16) unsigned short As[BM*32];
    __shared__ __align__(16) unsigned short Bs[BN*32];
    int tid = threadIdx.x;
    int lane = tid & 63;
    int wm = ((tid >> 7) & 1) * WM, wn = ((tid >> 6) & 1) * WN;
    int bm = blockIdx.y * BM, bn = blockIdx.x * BN;

    f32x4 acc[FM][FN] = {};

    int a_off = (wm + (lane & 15))*32 + (lane >> 4)*8;       // elems
    int b_off = (lane >> 4)*BN*8 + (wn + (lane & 15))*8;     // elems

    for (int k0 = 0; k0 < K; k0 += 32) {
#pragma unroll
        for (int i = 0; i < BM/64; ++i) {
            int s = tid + i*256;              // slot: m = s>>2, kq = s&3
            int m = s >> 2, kq = s & 3;
            gl_lds16(A + (size_t)(bm + m)*lda + k0 + kq*8, &As[s*8]);
        }
#pragma unroll
        for (int i = 0; i < BN/64; ++i) {
            int s = tid + i*256;              // slot: kb = s/BN, n = s%BN
            int kb = s / BN, n = s - kb*BN;
            gl_lds16(Wt + ((size_t)(k0/8 + kb)*N + bn + n)*8, &Bs[s*8]);
        }
        __syncthreads();
        bf16x8 af[FM], bfr[FN];
#pragma unroll
        for (int mi = 0; mi < FM; ++mi) af[mi] = *(const bf16x8*)&As[a_off + mi*512];
#pragma unroll
        for (int ni = 0; ni < FN; ++ni) bfr[ni] = *(const bf16x8*)&Bs[b_off + ni*128];
#pragma unroll
        for (int mi = 0; mi < FM; ++mi)
#pragma unroll
            for (int ni = 0; ni < FN; ++ni)
                acc[mi][ni] = __builtin_amdgcn_mfma_f32_16x16x32_bf16(af[mi], bfr[ni], acc[mi][ni], 0, 0, 0);
        __syncthreads();
    }

    int r0 = bm + wm + ((lane >> 4) << 2);
    int c0 = bn + wn + (lane & 15);
#pragma unroll
    for (int mi = 0; mi < FM; ++mi) {
#pragma unroll
        for (int ni = 0; ni < FN; ++ni) {
            int col = c0 + ni*16;
#pragma unroll
            for (int j = 0; j < 4; ++j) {
                int row = r0 + mi*16 + j;
                float c = acc[mi][ni][j] + bias[col];
                if (ACT == 4) {
                    int reg = col >> 9;
                    if (reg == 0) { c = (c > 0.f) ? c + 1.f : expf(c); }
                    else if (reg == 1) { c = (c > 0.f) ? c + 1.f : expf(c); c *= (maskv[row] != 0) ? 1.f : 0.f; }
                    Cb[(size_t)row*ldc + col] = f2bf(c);
                } else if (ACT == 3) {
                    c = 0.5f * c * (1.f + erff(c * 0.70710678118654752f));
                    Cb[(size_t)row*ldc + col] = f2bf(c);
                } else {
                    Cf[(size_t)row*ldc + col] = c;
                }
            }
        }
    }
}

// ---------------- per-chunk partial K^T V (64x64) and sum(k) (64), bf16 in ----------------
__global__ __launch_bounds__(256) void k_cpart(
        const unsigned short* __restrict__ QKVb, float* __restrict__ Mpart, float* __restrict__ Upart) {
    int b = blockIdx.x;
    int c = b % NCH, h = (b / NCH) % NHEAD, n = b / (NCH * NHEAD);
    const unsigned short* Kp = QKVb + (size_t)(n*SEQL + c*CHUNK)*QSTR + 512 + h*64;
    const unsigned short* Vp = Kp + 512;
    __shared__ float Ks[8][64], Vs[8][64];
    int tid = threadIdx.x;
    int dk = tid >> 2, dv0 = (tid & 3) * 16;
    int lr = tid >> 5, lc = (tid & 31) * 2;
    float acc[16] = {};
    float uacc = 0.f;
    for (int s0 = 0; s0 < CHUNK; s0 += 8) {
        ushort2 k2 = *(const ushort2*)(Kp + (size_t)(s0 + lr)*QSTR + lc);
        ushort2 v2 = *(const ushort2*)(Vp + (size_t)(s0 + lr)*QSTR + lc);
        Ks[lr][lc] = bf2f(k2.x); Ks[lr][lc+1] = bf2f(k2.y);
        Vs[lr][lc] = bf2f(v2.x); Vs[lr][lc+1] = bf2f(v2.y);
        __syncthreads();
#pragma unroll
        for (int ss = 0; ss < 8; ++ss) {
            float kk = Ks[ss][dk];
#pragma unroll
            for (int j = 0; j < 16; ++j) acc[j] += kk * Vs[ss][dv0 + j];
        }
        if (tid < 64) {
#pragma unroll
            for (int ss = 0; ss < 8; ++ss) uacc += Ks[ss][tid];
        }
        __syncthreads();
    }
    size_t base = ((size_t)(n*NHEAD + h)*NCH + c) * 4096;
#pragma unroll
    for (int j = 0; j < 16; ++j) Mpart[base + (size_t)dk*64 + dv0 + j] = acc[j];
    if (tid < 64) Upart[((size_t)(n*NHEAD + h)*NCH + c)*64 + tid] = uacc;
}

// ---------------- exclusive prefix scan over chunks ----------------
__global__ __launch_bounds__(256) void k_cscan(
        const float* __restrict__ Mpart, const float* __restrict__ Upart,
        float* __restrict__ Mpref, float* __restrict__ Upref) {
    int nh = blockIdx.x, tid = threadIdx.x;
    size_t base = (size_t)nh * NCH * 4096;
    for (int t = 0; t < 16; ++t) {
        int idx = t*256 + tid;
        float run = 0.f;
#pragma unroll
        for (int c = 0; c < NCH; ++c) {
            Mpref[base + (size_t)c*4096 + idx] = run;
            run += Mpart[base + (size_t)c*4096 + idx];
        }
    }
    if (tid < 64) {
        size_t ub = (size_t)nh * NCH * 64;
        float run = 0.f;
#pragma unroll
        for (int c = 0; c < NCH; ++c) {
            Upref[ub + c*64 + tid] = run;
            run += Upart[ub + c*64 + tid];
        }
    }
}

// ---------------- per-chunk attention, bf16 QKV in, bf16 out ----------------
__global__ __launch_bounds__(128) void k_cattend(
        const unsigned short* __restrict__ QKVb, const float* __restrict__ Mpref,
        const float* __restrict__ Upref, unsigned short* __restrict__ Ab) {
    int b = blockIdx.x;
    int c = b % NCH, h = (b / NCH) % NHEAD, n = b / (NCH * NHEAD);
    int tid = threadIdx.x;   // one row each
    __shared__ float Pp[64*64];
    __shared__ float wv[64];
    __shared__ float Kt[16][64];
    __shared__ float Vt[16][64];
    size_t pbase = ((size_t)(n*NHEAD + h)*NCH + c) * 4096;
#pragma unroll
    for (int t = 0; t < 32; ++t) Pp[t*128 + tid] = Mpref[pbase + t*128 + tid];
    if (tid < 64) wv[tid] = Upref[((size_t)(n*NHEAD + h)*NCH + c)*64 + tid];
    int rowbase = n*SEQL + c*CHUNK;
    int i = tid;
    float q[64];
    const unsigned short* qp = QKVb + (size_t)(rowbase + i)*QSTR + h*64;
#pragma unroll
    for (int d = 0; d < 64; d += 4) {
        ushort4 t4 = *(const ushort4*)(qp + d);
        q[d] = bf2f(t4.x); q[d+1] = bf2f(t4.y); q[d+2] = bf2f(t4.z); q[d+3] = bf2f(t4.w);
    }
    float acc[64] = {};
    float rowsum = 0.f;
    int jr = tid >> 3, jc = (tid & 7) * 8;
    for (int j0 = 0; j0 < CHUNK; j0 += 16) {
        const unsigned short* kp = QKVb + (size_t)(rowbase + j0 + jr)*QSTR + 512 + h*64 + jc;
        const unsigned short* vp = kp + 512;
        __syncthreads();
        {
            ushort4 a0 = *(const ushort4*)kp;     ushort4 a1 = *(const ushort4*)(kp + 4);
            ushort4 b0 = *(const ushort4*)vp;     ushort4 b1 = *(const ushort4*)(vp + 4);
            Kt[jr][jc+0] = bf2f(a0.x); Kt[jr][jc+1] = bf2f(a0.y); Kt[jr][jc+2] = bf2f(a0.z); Kt[jr][jc+3] = bf2f(a0.w);
            Kt[jr][jc+4] = bf2f(a1.x); Kt[jr][jc+5] = bf2f(a1.y); Kt[jr][jc+6] = bf2f(a1.z); Kt[jr][jc+7] = bf2f(a1.w);
            Vt[jr][jc+0] = bf2f(b0.x); Vt[jr][jc+1] = bf2f(b0.y); Vt[jr][jc+2] = bf2f(b0.z); Vt[jr][jc+3] = bf2f(b0.w);
            Vt[jr][jc+4] = bf2f(b1.x); Vt[jr][jc+5] = bf2f(b1.y); Vt[jr][jc+6] = bf2f(b1.z); Vt[jr][jc+7] = bf2f(b1.w);
        }
        __syncthreads();
        for (int jj = 0; jj < 16; ++jj) {
            int j = j0 + jj;
            if (j > i) break;
            float s = 0.f;
#pragma unroll
            for (int d = 0; d < 64; ++d) s += q[d] * Kt[jj][d];
            rowsum += s;
#pragma unroll
            for (int d = 0; d < 64; ++d) acc[d] += s * Vt[jj][d];
        }
    }
    for (int dd = 0; dd < 64; ++dd) {
        float qd = q[dd];
        const float* pr = &Pp[dd*64];
#pragma unroll
        for (int d = 0; d < 64; ++d) acc[d] += qd * pr[d];
    }
    float den = rowsum;
#pragma unroll
    for (int d = 0; d < 64; ++d) den += q[d] * wv[d];
    float z = 1.f / (den + ATT_EPS_F);
    unsigned short* op = Ab + (size_t)(rowbase + i)*EMB + h*64;
#pragma unroll
    for (int d = 0; d < 64; d += 4) {
        ushort4 o; o.x = f2bf(acc[d]*z); o.y = f2bf(acc[d+1]*z); o.z = f2bf(acc[d+2]*z); o.w = f2bf(acc[d+3]*z);
        *(ushort4*)(op + d) = o;
    }
}

// ---------------- residual + LayerNorm -> fp32 Y and bf16 Yb ----------------
__global__ __launch_bounds__(256) void k_ln(
        const float* __restrict__ X, const float* __restrict__ R,
        const float* __restrict__ g, const float* __restrict__ bb,
        float* __restrict__ Y, unsigned short* __restrict__ Yb) {
    int row = blockIdx.x, tid = threadIdx.x;
    float2 v = *(const float2*)(X + (size_t)row*EMB + tid*2);
    if (R) {
        float2 r = *(const float2*)(R + (size_t)row*EMB + tid*2);
        v.x += r.x; v.y += r.y;
    }
    float s = v.x + v.y, ss = v.x*v.x + v.y*v.y;
#pragma unroll
    for (int off = 32; off; off >>= 1) {
        s  += __shfl_down(s, off);
        ss += __shfl_down(ss, off);
    }
    __shared__ float sb[4], ssb[4];
    int wid = tid >> 6, lane = tid & 63;
    if (!lane) { sb[wid] = s; ssb[wid] = ss; }
    __syncthreads();
    float tot  = sb[0] + sb[1] + sb[2] + sb[3];
    float tots = ssb[0] + ssb[1] + ssb[2] + ssb[3];
    float mean = tot * (1.f/EMB);
    float var  = tots * (1.f/EMB) - mean*mean;
    float inv  = rsqrtf(var + LN_EPS_F);
    int e = tid*2;
    float2 o;
    o.x = (v.x - mean)*inv*g[e]   + bb[e];
    o.y = (v.y - mean)*inv*g[e+1] + bb[e+1];
    *(float2*)(Y + (size_t)row*EMB + e) = o;
    ushort2 ob; ob.x = f2bf(o.x); ob.y = f2bf(o.y);
    *(ushort2*)(Yb + (size_t)row*EMB + e) = ob;
}

// ---------------- head: out = X @ Wh  (512 -> 17) ----------------
__global__ void k_head(const float* __restrict__ X, const float* __restrict__ Wh,
                       float* __restrict__ out) {
    int idx = blockIdx.x * blockDim.x + threadIdx.x;
    if (idx >= NROWS*17) return;
    int row = idx / 17, c = idx - row*17;
    const float* xp = X + (size_t)row*EMB;
    float acc = 0.f;
    for (int k = 0; k < EMB; ++k) acc += xp[k] * Wh[k*17 + c];
    out[idx] = acc;
}

extern "C" void kernel_launch(void* const* d_in, const int* in_sizes, int n_in,
                              void* d_out, int out_size, void* d_ws, size_t ws_size,
                              hipStream_t stream) {
    (void)in_sizes; (void)n_in; (void)out_size; (void)ws_size;
    const int*   value = (const int*)d_in[0];
    const int*   depth = (const int*)d_in[1];
    const int*   pos   = (const int*)d_in[2];
    const float* sos   = (const float*)d_in[3];
    const float* tok   = (const float*)d_in[4];
    const float* dep   = (const float*)d_in[5];
    const float* spa   = (const float*)d_in[6];
    const float* Wq0   = (const float*)d_in[7];
    const float* Wk0   = (const float*)d_in[8];
    const float* Wv0   = (const float*)d_in[9];
    const float* Wo0   = (const float*)d_in[10];
    const float* bq0   = (const float*)d_in[11];
    const float* bk0   = (const float*)d_in[12];
    const float* bv0   = (const float*)d_in[13];
    const float* bo0   = (const float*)d_in[14];
    const float* ln1g  = (const float*)d_in[15];
    const float* ln1b  = (const float*)d_in[16];
    const float* ln2g  = (const float*)d_in[17];
    const float* ln2b  = (const float*)d_in[18];
    const float* W10   = (const float*)d_in[19];
    const float* b10   = (const float*)d_in[20];
    const float* W20   = (const float*)d_in[21];
    const float* b20   = (const float*)d_in[22];
    const float* lnfg  = (const float*)d_in[23];
    const float* lnfb  = (const float*)d_in[24];
    const float* Wh    = (const float*)d_in[25];
    float* out = (float*)d_out;
    float* ws  = (float*)d_ws;

    // workspace layout (float units); aliases verified against per-phase lifetimes
    float*          X     = ws;                                  // [0, 1048576)
    unsigned short* Xb    = (unsigned short*)(ws + 1048576);     // 524288 f
    unsigned short* QKVb  = (unsigned short*)(ws + 1572864);     // 1572864 f (2048x1536 bf16)
    unsigned short* Ab    = (unsigned short*)(ws + 3145728);     // 524288 f
    unsigned short* Hb    = (unsigned short*)(ws + 1572864);     // alias QKVb+Ab (2048x2048 bf16)
    float*          Mpart = ws + 3670016;                        // 524288 f (alias AO)
    float*          Mpref = ws + 4194304;                        // 524288 f (alias AO)
    float*          AO    = ws + 3670016;                        // 1048576 f
    float*          Upart = ws + 4718592;                        // 8192 f
    float*          Upref = ws + 4726784;                        // 8192 f
    float*          bqkv  = ws + 4734976;                        // 6144 f
    unsigned short* qkvT  = (unsigned short*)(ws + 4741120);     // per-layer weights bf16
    unsigned short* woT   = qkvT + 786432;
    unsigned short* w1T   = qkvT + 1048576;
    unsigned short* w2T   = qkvT + 2097152;                      // end: 6313984 f = 25.3 MB

    k_embed<<<NROWS, 128, 0, stream>>>(value, depth, pos, sos, tok, dep, spa, X, Xb);
    k_bpack<<<dim3(6,4), 256, 0, stream>>>(bq0, bk0, bv0, bqkv);

    for (int L = 0; L < NLAYER; ++L) {
        k_wconv<<<1536, 256, 0, stream>>>(
            Wq0 + (size_t)L*EMB*EMB, Wk0 + (size_t)L*EMB*EMB, Wv0 + (size_t)L*EMB*EMB,
            Wo0 + (size_t)L*EMB*EMB, W10 + (size_t)L*EMB*FFDIM, W20 + (size_t)L*FFDIM*EMB,
            qkvT, woT, w1T, w2T);

        k_mgemm<128,128,4><<<dim3(12,16), 256, 0, stream>>>(
            Xb, qkvT, bqkv + L*1536, value, nullptr, QKVb, 1536, 512, 512, 1536);

        k_cpart<<<NBATCH*NHEAD*NCH, 256, 0, stream>>>(QKVb, Mpart, Upart);
        k_cscan<<<NBATCH*NHEAD, 256, 0, stream>>>(Mpart, Upart, Mpref, Upref);
        k_cattend<<<NBATCH*NHEAD*NCH, 128, 0, stream>>>(QKVb, Mpref, Upref, Ab);

        k_mgemm<64,64,0><<<dim3(8,32), 256, 0, stream>>>(
            Ab, woT, bo0 + (size_t)L*EMB, nullptr, AO, nullptr, 512, 512, 512, 512);
        k_ln<<<NROWS, 256, 0, stream>>>(X, AO, ln1g + (size_t)L*EMB, ln1b + (size_t)L*EMB, X, Xb);

        k_mgemm<128,128,3><<<dim3(16,16), 256, 0, stream>>>(
            Xb, w1T, b10 + (size_t)L*FFDIM, nullptr, nullptr, Hb, 2048, 512, 512, 2048);
        k_mgemm<64,64,0><<<dim3(8,32), 256, 0, stream>>>(
            Hb, w2T, b20 + (size_t)L*EMB, nullptr, AO, nullptr, 512, 2048, 2048, 512);
        k_ln<<<NROWS, 256, 0, stream>>>(X, AO, ln2g + (size_t)L*EMB, ln2b + (size_t)L*EMB, X, Xb);
    }
    k_ln<<<NROWS, 256, 0, stream>>>(X, nullptr, lnfg, lnfb, X, Xb);
    k_head<<<(NROWS*17 + 255)/256, 256, 0, stream>>>(X, Wh, out);
}

// Round 3
// 583.023 us; speedup vs baseline: 3.0074x; 1.6248x over previous
//
#include <hip/hip_runtime.h>
#include <math.h>

#define EMB 512
#define SEQL 1024
#define NBATCH 2
#define NHEAD 8
#define FFDIM 2048
#define NLAYER 4
#define NROWS (NBATCH*SEQL)
#define CHUNK 128
#define NCH (SEQL/CHUNK)
#define QSTR 1536
#define LN_EPS_F 1e-5f
#define ATT_EPS_F 1e-6f

typedef __bf16 bf16x8 __attribute__((ext_vector_type(8)));
typedef float f32x4 __attribute__((ext_vector_type(4)));

__device__ __forceinline__ unsigned short f2bf(float f) {
    unsigned int u = __float_as_uint(f);
    u += 0x7FFFu + ((u >> 16) & 1u);
    return (unsigned short)(u >> 16);
}
__device__ __forceinline__ float bf2f(unsigned short x) {
    return __uint_as_float(((unsigned int)x) << 16);
}
__device__ __forceinline__ void gl_lds16(const unsigned short* g, unsigned short* l) {
    __builtin_amdgcn_global_load_lds(
        (__attribute__((address_space(1))) void*)const_cast<unsigned short*>(g),
        (__attribute__((address_space(3))) void*)l, 16, 0, 0);
}

// ---------------- embedding + shift-right(SOS), writes fp32 X and bf16 Xb ----------------
__global__ void k_embed(const int* __restrict__ value, const int* __restrict__ depth,
                        const int* __restrict__ pos, const float* __restrict__ sos,
                        const float* __restrict__ tok, const float* __restrict__ dep,
                        const float* __restrict__ spa, float* __restrict__ X,
                        unsigned short* __restrict__ Xb) {
    int row = blockIdx.x;
    int n = row / SEQL, s = row % SEQL;
    int e = threadIdx.x * 4;
    float4 o;
    if (s == 0) {
        o = *(const float4*)(sos + e);
    } else {
        int sp = s - 1;
        int tv = value[n*SEQL + sp];
        int dv = depth[n*SEQL + sp];
        float4 a = *(const float4*)(tok + (size_t)tv*EMB + e);
        float4 b = *(const float4*)(dep + (size_t)dv*EMB + e);
        o.x = a.x+b.x; o.y = a.y+b.y; o.z = a.z+b.z; o.w = a.w+b.w;
#pragma unroll
        for (int ax = 0; ax < 3; ++ax) {
            int p = pos[((size_t)ax*NBATCH + n)*SEQL + sp];
            float4 c = *(const float4*)(spa + ((size_t)ax*257 + p)*EMB + e);
            o.x += c.x; o.y += c.y; o.z += c.z; o.w += c.w;
        }
    }
    *(float4*)(X + (size_t)row*EMB + e) = o;
    ushort4 ob; ob.x = f2bf(o.x); ob.y = f2bf(o.y); ob.z = f2bf(o.z); ob.w = f2bf(o.w);
    *(ushort4*)(Xb + (size_t)row*EMB + e) = ob;
}

// ---------------- weight convert: fp32 [K][Ns] -> bf16 packed [K/8][Nd][8] ----------------
__global__ __launch_bounds__(256) void k_wconv(
        const float* __restrict__ Wq, const float* __restrict__ Wk, const float* __restrict__ Wv,
        const float* __restrict__ Wo, const float* __restrict__ W1, const float* __restrict__ W2,
        unsigned short* __restrict__ qkvT, unsigned short* __restrict__ woT,
        unsigned short* __restrict__ w1T, unsigned short* __restrict__ w2T) {
    int idx = blockIdx.x*256 + threadIdx.x;
    const float* src; unsigned short* dst; size_t soff; size_t doff;
    if (idx < 131072) {                      // 4 x (64 kb x 512 n)
        int sub = idx >> 15, t = idx & 32767;
        int kb = t >> 9, n = t & 511;
        src = (sub == 0) ? Wq : (sub == 1) ? Wk : (sub == 2) ? Wv : Wo;
        soff = (size_t)kb*8*512 + n;
        if (sub < 3) { dst = qkvT; doff = ((size_t)kb*1536 + sub*512 + n)*8; }
        else         { dst = woT;  doff = ((size_t)kb*512 + n)*8; }
        unsigned int p[4];
#pragma unroll
        for (int t2 = 0; t2 < 4; ++t2) {
            unsigned int lo = f2bf(src[soff + (size_t)(2*t2)*512]);
            unsigned int hi = f2bf(src[soff + (size_t)(2*t2+1)*512]);
            p[t2] = lo | (hi << 16);
        }
        *(uint4*)(dst + doff) = make_uint4(p[0], p[1], p[2], p[3]);
    } else if (idx < 262144) {               // W1: 64 kb x 2048 n
        int t = idx - 131072;
        int kb = t >> 11, n = t & 2047;
        soff = (size_t)kb*8*2048 + n;
        doff = ((size_t)kb*2048 + n)*8;
        unsigned int p[4];
#pragma unroll
        for (int t2 = 0; t2 < 4; ++t2) {
            unsigned int lo = f2bf(W1[soff + (size_t)(2*t2)*2048]);
            unsigned int hi = f2bf(W1[soff + (size_t)(2*t2+1)*2048]);
            p[t2] = lo | (hi << 16);
        }
        *(uint4*)(w1T + doff) = make_uint4(p[0], p[1], p[2], p[3]);
    } else {                                  // W2: 256 kb x 512 n
        int t = idx - 262144;
        int kb = t >> 9, n = t & 511;
        soff = (size_t)kb*8*512 + n;
        doff = ((size_t)kb*512 + n)*8;
        unsigned int p[4];
#pragma unroll
        for (int t2 = 0; t2 < 4; ++t2) {
            unsigned int lo = f2bf(W2[soff + (size_t)(2*t2)*512]);
            unsigned int hi = f2bf(W2[soff + (size_t)(2*t2+1)*512]);
            p[t2] = lo | (hi << 16);
        }
        *(uint4*)(w2T + doff) = make_uint4(p[0], p[1], p[2], p[3]);
    }
}

// ---------------- pack qkv biases [L][1536] ----------------
__global__ void k_bpack(const float* __restrict__ bq, const float* __restrict__ bk,
                        const float* __restrict__ bv, float* __restrict__ outp) {
    int c = blockIdx.x*256 + threadIdx.x;
    int L = blockIdx.y;
    float v = (c < 512) ? bq[L*512 + c] : (c < 1024) ? bk[L*512 + c - 512] : bv[L*512 + c - 1024];
    outp[L*1536 + c] = v;
}

// ---------------- bf16 MFMA GEMM ----------------
template<int BM, int BN, int ACT>
__global__ __launch_bounds__(256) void k_mgemm(
        const unsigned short* __restrict__ A, const unsigned short* __restrict__ Wt,
        const float* __restrict__ bias, const int* __restrict__ maskv,
        float* __restrict__ Cf, unsigned short* __restrict__ Cb,
        int N, int K, int lda, int ldc) {
    constexpr int WM = BM/2, WN = BN/2;
    constexpr int FM = WM/16, FN = WN/16;
    __shared__ __align__(16) unsigned short As[BM*32];
    __shared__ __align__(16) unsigned short Bs[BN*32];
    int tid = threadIdx.x;
    int lane = tid & 63;
    int wm = ((tid >> 7) & 1) * WM, wn = ((tid >> 6) & 1) * WN;
    int bm = blockIdx.y * BM, bn = blockIdx.x * BN;

    f32x4 acc[FM][FN] = {};

    int a_off = (wm + (lane & 15))*32 + (lane >> 4)*8;
    int b_off = (lane >> 4)*BN*8 + (wn + (lane & 15))*8;

    for (int k0 = 0; k0 < K; k0 += 32) {
#pragma unroll
        for (int i = 0; i < BM/64; ++i) {
            int s = tid + i*256;
            int m = s >> 2, kq = s & 3;
            gl_lds16(A + (size_t)(bm + m)*lda + k0 + kq*8, &As[s*8]);
        }
#pragma unroll
        for (int i = 0; i < BN/64; ++i) {
            int s = tid + i*256;
            int kb = s / BN, n = s - kb*BN;
            gl_lds16(Wt + ((size_t)(k0/8 + kb)*N + bn + n)*8, &Bs[s*8]);
        }
        __syncthreads();
        bf16x8 af[FM], bfr[FN];
#pragma unroll
        for (int mi = 0; mi < FM; ++mi) af[mi] = *(const bf16x8*)&As[a_off + mi*512];
#pragma unroll
        for (int ni = 0; ni < FN; ++ni) bfr[ni] = *(const bf16x8*)&Bs[b_off + ni*128];
#pragma unroll
        for (int mi = 0; mi < FM; ++mi)
#pragma unroll
            for (int ni = 0; ni < FN; ++ni)
                acc[mi][ni] = __builtin_amdgcn_mfma_f32_16x16x32_bf16(af[mi], bfr[ni], acc[mi][ni], 0, 0, 0);
        __syncthreads();
    }

    int r0 = bm + wm + ((lane >> 4) << 2);
    int c0 = bn + wn + (lane & 15);
#pragma unroll
    for (int mi = 0; mi < FM; ++mi) {
#pragma unroll
        for (int ni = 0; ni < FN; ++ni) {
            int col = c0 + ni*16;
#pragma unroll
            for (int j = 0; j < 4; ++j) {
                int row = r0 + mi*16 + j;
                float c = acc[mi][ni][j] + bias[col];
                if (ACT == 4) {
                    int reg = col >> 9;
                    if (reg == 0) { c = (c > 0.f) ? c + 1.f : expf(c); }
                    else if (reg == 1) { c = (c > 0.f) ? c + 1.f : expf(c); c *= (maskv[row] != 0) ? 1.f : 0.f; }
                    Cb[(size_t)row*ldc + col] = f2bf(c);
                } else if (ACT == 3) {
                    c = 0.5f * c * (1.f + erff(c * 0.70710678118654752f));
                    Cb[(size_t)row*ldc + col] = f2bf(c);
                } else {
                    Cf[(size_t)row*ldc + col] = c;
                }
            }
        }
    }
}

// ---------------- per-chunk partial K^T V (64x64) and sum(k) (64), bf16 in ----------------
__global__ __launch_bounds__(256) void k_cpart(
        const unsigned short* __restrict__ QKVb, float* __restrict__ Mpart, float* __restrict__ Upart) {
    int b = blockIdx.x;
    int c = b % NCH, h = (b / NCH) % NHEAD, n = b / (NCH * NHEAD);
    const unsigned short* Kp = QKVb + (size_t)(n*SEQL + c*CHUNK)*QSTR + 512 + h*64;
    const unsigned short* Vp = Kp + 512;
    __shared__ float Ks[8][64], Vs[8][64];
    int tid = threadIdx.x;
    int dk = tid >> 2, dv0 = (tid & 3) * 16;
    int lr = tid >> 5, lc = (tid & 31) * 2;
    float acc[16] = {};
    float uacc = 0.f;
    for (int s0 = 0; s0 < CHUNK; s0 += 8) {
        ushort2 k2 = *(const ushort2*)(Kp + (size_t)(s0 + lr)*QSTR + lc);
        ushort2 v2 = *(const ushort2*)(Vp + (size_t)(s0 + lr)*QSTR + lc);
        Ks[lr][lc] = bf2f(k2.x); Ks[lr][lc+1] = bf2f(k2.y);
        Vs[lr][lc] = bf2f(v2.x); Vs[lr][lc+1] = bf2f(v2.y);
        __syncthreads();
#pragma unroll
        for (int ss = 0; ss < 8; ++ss) {
            float kk = Ks[ss][dk];
#pragma unroll
            for (int j = 0; j < 16; ++j) acc[j] += kk * Vs[ss][dv0 + j];
        }
        if (tid < 64) {
#pragma unroll
            for (int ss = 0; ss < 8; ++ss) uacc += Ks[ss][tid];
        }
        __syncthreads();
    }
    size_t base = ((size_t)(n*NHEAD + h)*NCH + c) * 4096;
#pragma unroll
    for (int j = 0; j < 16; ++j) Mpart[base + (size_t)dk*64 + dv0 + j] = acc[j];
    if (tid < 64) Upart[((size_t)(n*NHEAD + h)*NCH + c)*64 + tid] = uacc;
}

// ---------------- exclusive prefix scan over chunks ----------------
__global__ __launch_bounds__(256) void k_cscan(
        const float* __restrict__ Mpart, const float* __restrict__ Upart,
        float* __restrict__ Mpref, float* __restrict__ Upref) {
    int nh = blockIdx.x, tid = threadIdx.x;
    size_t base = (size_t)nh * NCH * 4096;
    for (int t = 0; t < 16; ++t) {
        int idx = t*256 + tid;
        float run = 0.f;
#pragma unroll
        for (int c = 0; c < NCH; ++c) {
            Mpref[base + (size_t)c*4096 + idx] = run;
            run += Mpart[base + (size_t)c*4096 + idx];
        }
    }
    if (tid < 64) {
        size_t ub = (size_t)nh * NCH * 64;
        float run = 0.f;
#pragma unroll
        for (int c = 0; c < NCH; ++c) {
            Upref[ub + c*64 + tid] = run;
            run += Upart[ub + c*64 + tid];
        }
    }
}

// ---------------- MFMA chunk attention: 8 waves, 16 q-rows/wave ----------------
// Stage1: S = QK^T (frags direct from global), mask, fp32 rowsum, S->bf16 in wave-private LDS.
// Stage2: O = S@V (V transposed in LDS; prefix P appended as pseudo-keys j=128..191
//         with A-frags = the stage-1 Q frags). den = rowsum + q.w (all fp32).
__global__ __launch_bounds__(512) void k_cattend(
        const unsigned short* __restrict__ QKVb, const float* __restrict__ Mpref,
        const float* __restrict__ Upref, unsigned short* __restrict__ Ab) {
    int b = blockIdx.x;
    int c = b % NCH, h = (b / NCH) % NHEAD, n = b / (NCH * NHEAD);
    int tid = threadIdx.x;
    int wid = tid >> 6, lane = tid & 63;
    int l15 = lane & 15, lg = lane >> 4;
    __shared__ __align__(16) unsigned short Vt[64*200];   // [vd][j] j=0..191 (V | P)
    __shared__ __align__(16) unsigned short St[11264];    // per-wave S strips (var stride)
    __shared__ float wf[64];
    size_t pbase = ((size_t)(n*NHEAD + h)*NCH + c) * 4096;
    size_t ubase = ((size_t)(n*NHEAD + h)*NCH + c) * 64;
    int rowbase = n*SEQL + c*CHUNK;

    // ---- stage Vt: j<128 = V[j][vd]; j=128+d = P[d][vd] ----
    {
        int j = tid & 127, vd0 = (tid >> 7) * 16;
        const unsigned short* vp = QKVb + (size_t)(rowbase + j)*QSTR + 1024 + h*64 + vd0;
        uint4 u0 = *(const uint4*)vp;
        uint4 u1 = *(const uint4*)(vp + 8);
        const unsigned short* e0 = (const unsigned short*)&u0;
        const unsigned short* e1 = (const unsigned short*)&u1;
#pragma unroll
        for (int t = 0; t < 8; ++t) Vt[(vd0 + t)*200 + j] = e0[t];
#pragma unroll
        for (int t = 0; t < 8; ++t) Vt[(vd0 + 8 + t)*200 + j] = e1[t];
    }
    {
        int d = tid & 63, vd0 = (tid >> 6) * 8;
        const float* pp = Mpref + pbase + (size_t)d*64 + vd0;
        float4 p0 = *(const float4*)pp;
        float4 p1 = *(const float4*)(pp + 4);
        Vt[(vd0+0)*200 + 128 + d] = f2bf(p0.x);
        Vt[(vd0+1)*200 + 128 + d] = f2bf(p0.y);
        Vt[(vd0+2)*200 + 128 + d] = f2bf(p0.z);
        Vt[(vd0+3)*200 + 128 + d] = f2bf(p0.w);
        Vt[(vd0+4)*200 + 128 + d] = f2bf(p1.x);
        Vt[(vd0+5)*200 + 128 + d] = f2bf(p1.y);
        Vt[(vd0+6)*200 + 128 + d] = f2bf(p1.z);
        Vt[(vd0+7)*200 + 128 + d] = f2bf(p1.w);
    }
    if (tid < 64) wf[tid] = Upref[ubase + tid];

    // ---- stage 1: S = Q K^T ----
    int r0 = wid * 16;
    int koff = lg * 8;
    const unsigned short* qp = QKVb + (size_t)(rowbase + r0 + l15)*QSTR + h*64 + koff;
    uint4 uq0 = *(const uint4*)qp;
    uint4 uq1 = *(const uint4*)(qp + 32);
    bf16x8 aq0 = *(bf16x8*)&uq0;
    bf16x8 aq1 = *(bf16x8*)&uq1;

    int nact = (wid & ~1) + 2;                      // causal: N-tiles 0..nact-1
    int sstr_ = 32*((wid >> 1) + 1) + 8;            // strip stride (elems)
    int p_ = wid >> 1;
    int sig = p_*(p_+1) + (wid & 1)*(p_+1);
    int stoff_ = 128*wid + 512*sig;                 // strip base (elems)

    float rsum[4] = {0.f, 0.f, 0.f, 0.f};
    for (int nt = 0; nt < nact; ++nt) {
        int j0 = nt*16;
        const unsigned short* kp = QKVb + (size_t)(rowbase + j0 + l15)*QSTR + 512 + h*64 + koff;
        uint4 uk0 = *(const uint4*)kp;
        uint4 uk1 = *(const uint4*)(kp + 32);
        f32x4 s = {0.f, 0.f, 0.f, 0.f};
        s = __builtin_amdgcn_mfma_f32_16x16x32_bf16(aq0, *(bf16x8*)&uk0, s, 0, 0, 0);
        s = __builtin_amdgcn_mfma_f32_16x16x32_bf16(aq1, *(bf16x8*)&uk1, s, 0, 0, 0);
        int jcol = j0 + l15;
#pragma unroll
        for (int r = 0; r < 4; ++r) {
            int irow = r0 + lg*4 + r;
            float sv = (jcol <= irow) ? s[r] : 0.f;
            rsum[r] += sv;
            St[stoff_ + (lg*4 + r)*sstr_ + jcol] = f2bf(sv);
        }
    }
    __syncthreads();

    // ---- q . w (fp32 den part) ----
    float qw = 0.f;
    const unsigned short* q0e = (const unsigned short*)&uq0;
    const unsigned short* q1e = (const unsigned short*)&uq1;
#pragma unroll
    for (int jj = 0; jj < 8; ++jj) {
        qw += bf2f(q0e[jj]) * wf[koff + jj];
        qw += bf2f(q1e[jj]) * wf[32 + koff + jj];
    }
    qw += __shfl_xor(qw, 16);
    qw += __shfl_xor(qw, 32);

    // ---- stage 2: O = S @ V_ext ----
    f32x4 o[4] = {};
    int nkr = (wid >> 1) + 1;                       // real k-steps (causal skip)
    for (int ks = 0; ks < nkr; ++ks) {
        bf16x8 as = *(bf16x8*)&St[stoff_ + l15*sstr_ + ks*32 + koff];
#pragma unroll
        for (int nt = 0; nt < 4; ++nt) {
            bf16x8 bv = *(bf16x8*)&Vt[(nt*16 + l15)*200 + ks*32 + koff];
            o[nt] = __builtin_amdgcn_mfma_f32_16x16x32_bf16(as, bv, o[nt], 0, 0, 0);
        }
    }
#pragma unroll
    for (int kk = 0; kk < 2; ++kk) {
        bf16x8 as = kk ? aq1 : aq0;                 // pseudo keys: S_ext = q_d
#pragma unroll
        for (int nt = 0; nt < 4; ++nt) {
            bf16x8 bv = *(bf16x8*)&Vt[(nt*16 + l15)*200 + 128 + kk*32 + koff];
            o[nt] = __builtin_amdgcn_mfma_f32_16x16x32_bf16(as, bv, o[nt], 0, 0, 0);
        }
    }

    // ---- rowsum reduce + epilogue ----
#pragma unroll
    for (int r = 0; r < 4; ++r) {
        float v = rsum[r];
        v += __shfl_xor(v, 1); v += __shfl_xor(v, 2);
        v += __shfl_xor(v, 4); v += __shfl_xor(v, 8);
        rsum[r] = v;
    }
#pragma unroll
    for (int r = 0; r < 4; ++r) {
        float qwr = __shfl(qw, lg*4 + r);
        float z = 1.f / (rsum[r] + qwr + ATT_EPS_F);
        int orow = rowbase + r0 + lg*4 + r;
        unsigned short* op = Ab + (size_t)orow*EMB + h*64 + l15;
#pragma unroll
        for (int nt = 0; nt < 4; ++nt)
            op[nt*16] = f2bf(o[nt][r] * z);
    }
}

// ---------------- residual + LayerNorm -> fp32 Y and bf16 Yb ----------------
__global__ __launch_bounds__(256) void k_ln(
        const float* __restrict__ X, const float* __restrict__ R,
        const float* __restrict__ g, const float* __restrict__ bb,
        float* __restrict__ Y, unsigned short* __restrict__ Yb) {
    int row = blockIdx.x, tid = threadIdx.x;
    float2 v = *(const float2*)(X + (size_t)row*EMB + tid*2);
    if (R) {
        float2 r = *(const float2*)(R + (size_t)row*EMB + tid*2);
        v.x += r.x; v.y += r.y;
    }
    float s = v.x + v.y, ss = v.x*v.x + v.y*v.y;
#pragma unroll
    for (int off = 32; off; off >>= 1) {
        s  += __shfl_down(s, off);
        ss += __shfl_down(ss, off);
    }
    __shared__ float sb[4], ssb[4];
    int wid = tid >> 6, lane = tid & 63;
    if (!lane) { sb[wid] = s; ssb[wid] = ss; }
    __syncthreads();
    float tot  = sb[0] + sb[1] + sb[2] + sb[3];
    float tots = ssb[0] + ssb[1] + ssb[2] + ssb[3];
    float mean = tot * (1.f/EMB);
    float var  = tots * (1.f/EMB) - mean*mean;
    float inv  = rsqrtf(var + LN_EPS_F);
    int e = tid*2;
    float2 o;
    o.x = (v.x - mean)*inv*g[e]   + bb[e];
    o.y = (v.y - mean)*inv*g[e+1] + bb[e+1];
    *(float2*)(Y + (size_t)row*EMB + e) = o;
    ushort2 ob; ob.x = f2bf(o.x); ob.y = f2bf(o.y);
    *(ushort2*)(Yb + (size_t)row*EMB + e) = ob;
}

// ---------------- head: out = X @ Wh  (512 -> 17) ----------------
__global__ void k_head(const float* __restrict__ X, const float* __restrict__ Wh,
                       float* __restrict__ out) {
    int idx = blockIdx.x * blockDim.x + threadIdx.x;
    if (idx >= NROWS*17) return;
    int row = idx / 17, c = idx - row*17;
    const float* xp = X + (size_t)row*EMB;
    float acc = 0.f;
    for (int k = 0; k < EMB; ++k) acc += xp[k] * Wh[k*17 + c];
    out[idx] = acc;
}

extern "C" void kernel_launch(void* const* d_in, const int* in_sizes, int n_in,
                              void* d_out, int out_size, void* d_ws, size_t ws_size,
                              hipStream_t stream) {
    (void)in_sizes; (void)n_in; (void)out_size; (void)ws_size;
    const int*   value = (const int*)d_in[0];
    const int*   depth = (const int*)d_in[1];
    const int*   pos   = (const int*)d_in[2];
    const float* sos   = (const float*)d_in[3];
    const float* tok   = (const float*)d_in[4];
    const float* dep   = (const float*)d_in[5];
    const float* spa   = (const float*)d_in[6];
    const float* Wq0   = (const float*)d_in[7];
    const float* Wk0   = (const float*)d_in[8];
    const float* Wv0   = (const float*)d_in[9];
    const float* Wo0   = (const float*)d_in[10];
    const float* bq0   = (const float*)d_in[11];
    const float* bk0   = (const float*)d_in[12];
    const float* bv0   = (const float*)d_in[13];
    const float* bo0   = (const float*)d_in[14];
    const float* ln1g  = (const float*)d_in[15];
    const float* ln1b  = (const float*)d_in[16];
    const float* ln2g  = (const float*)d_in[17];
    const float* ln2b  = (const float*)d_in[18];
    const float* W10   = (const float*)d_in[19];
    const float* b10   = (const float*)d_in[20];
    const float* W20   = (const float*)d_in[21];
    const float* b20   = (const float*)d_in[22];
    const float* lnfg  = (const float*)d_in[23];
    const float* lnfb  = (const float*)d_in[24];
    const float* Wh    = (const float*)d_in[25];
    float* out = (float*)d_out;
    float* ws  = (float*)d_ws;

    float*          X     = ws;
    unsigned short* Xb    = (unsigned short*)(ws + 1048576);
    unsigned short* QKVb  = (unsigned short*)(ws + 1572864);
    unsigned short* Ab    = (unsigned short*)(ws + 3145728);
    unsigned short* Hb    = (unsigned short*)(ws + 1572864);
    float*          Mpart = ws + 3670016;
    float*          Mpref = ws + 4194304;
    float*          AO    = ws + 3670016;
    float*          Upart = ws + 4718592;
    float*          Upref = ws + 4726784;
    float*          bqkv  = ws + 4734976;
    unsigned short* qkvT  = (unsigned short*)(ws + 4741120);
    unsigned short* woT   = qkvT + 786432;
    unsigned short* w1T   = qkvT + 1048576;
    unsigned short* w2T   = qkvT + 2097152;

    k_embed<<<NROWS, 128, 0, stream>>>(value, depth, pos, sos, tok, dep, spa, X, Xb);
    k_bpack<<<dim3(6,4), 256, 0, stream>>>(bq0, bk0, bv0, bqkv);

    for (int L = 0; L < NLAYER; ++L) {
        k_wconv<<<1536, 256, 0, stream>>>(
            Wq0 + (size_t)L*EMB*EMB, Wk0 + (size_t)L*EMB*EMB, Wv0 + (size_t)L*EMB*EMB,
            Wo0 + (size_t)L*EMB*EMB, W10 + (size_t)L*EMB*FFDIM, W20 + (size_t)L*FFDIM*EMB,
            qkvT, woT, w1T, w2T);

        k_mgemm<128,128,4><<<dim3(12,16), 256, 0, stream>>>(
            Xb, qkvT, bqkv + L*1536, value, nullptr, QKVb, 1536, 512, 512, 1536);

        k_cpart<<<NBATCH*NHEAD*NCH, 256, 0, stream>>>(QKVb, Mpart, Upart);
        k_cscan<<<NBATCH*NHEAD, 256, 0, stream>>>(Mpart, Upart, Mpref, Upref);
        k_cattend<<<NBATCH*NHEAD*NCH, 512, 0, stream>>>(QKVb, Mpref, Upref, Ab);

        k_mgemm<64,64,0><<<dim3(8,32), 256, 0, stream>>>(
            Ab, woT, bo0 + (size_t)L*EMB, nullptr, AO, nullptr, 512, 512, 512, 512);
        k_ln<<<NROWS, 256, 0, stream>>>(X, AO, ln1g + (size_t)L*EMB, ln1b + (size_t)L*EMB, X, Xb);

        k_mgemm<128,128,3><<<dim3(16,16), 256, 0, stream>>>(
            Xb, w1T, b10 + (size_t)L*FFDIM, nullptr, nullptr, Hb, 2048, 512, 512, 2048);
        k_mgemm<64,64,0><<<dim3(8,32), 256, 0, stream>>>(
            Hb, w2T, b20 + (size_t)L*EMB, nullptr, AO, nullptr, 512, 2048, 2048, 512);
        k_ln<<<NROWS, 256, 0, stream>>>(X, AO, ln2g + (size_t)L*EMB, ln2b + (size_t)L*EMB, X, Xb);
    }
    k_ln<<<NROWS, 256, 0, stream>>>(X, nullptr, lnfg, lnfb, X, Xb);
    k_head<<<(NROWS*17 + 255)/256, 256, 0, stream>>>(X, Wh, out);
}